// Round 3
// baseline (1055.490 us; speedup 1.0000x reference)
//
#include <hip/hip_runtime.h>

#define DIMC   3072
#define HEADS  24
#define HD     128
#define FF     12288
#define S_IMG  1024
#define S_TXT  256
#define S_TOT  1280
#define EPSF   1e-6f

typedef __attribute__((ext_vector_type(8))) short bf16x8;
typedef __attribute__((ext_vector_type(4))) float f32x4;
typedef __attribute__((ext_vector_type(4))) float float4v;

__device__ __forceinline__ unsigned short f2bf(float f) {
    union { float f; unsigned u; } c; c.f = f;
    unsigned u = c.u;
    unsigned r = (u + 0x7fffu + ((u >> 16) & 1u)) >> 16;  // RTNE
    return (unsigned short)r;
}
__device__ __forceinline__ float b2f(unsigned short h) {
    union { unsigned u; float f; } c; c.u = ((unsigned)h) << 16;
    return c.f;
}

#define GLL16(gsrc, ldst)                                                     \
    __builtin_amdgcn_global_load_lds(                                         \
        (const __attribute__((address_space(1))) void*)(gsrc),                \
        (__attribute__((address_space(3))) void*)(ldst), 16, 0, 0)

struct GemmArgs {
    const unsigned short* A;
    const void* B;
    const float* bias;
    void* out;
    const float* base;
    const float* gate;
};

// ---------------------------------------------------------------------------
// C = A(MxK,bf16) * B(NxK)^T + bias. 128x128 tile, BK=64, 4 waves (2x2).
// global_load_lds staging (m97 structure): A bf16 -> LDS; B fp32 staged RAW
// into LDS and converted to bf16 on the ds_read side (or bf16 direct).
// Swizzle: linear LDS dest, inverse-swizzled global source, XOR on read.
// EPI: 0 fp32 store; 1 bf16 store; 2 gelu(tanh)->bf16; 3 base + gate*v -> fp32
// ---------------------------------------------------------------------------
template<int EPI, bool BF16B>
__global__ __launch_bounds__(256)
void gemm_bt(GemmArgs g0, GemmArgs g1, int ysplit,
             int K, int lda, int ldb, int ldout,
             long batchA, long batchB, long batchOut)
{
    constexpr int ASZ = 128 * 64 * 2;                    // 16 KB
    constexpr int BSZ = BF16B ? 128 * 64 * 2 : 128 * 64 * 4;
    __shared__ __align__(16) char smem[2 * ASZ + 2 * BSZ];
    char* smemA = smem;
    char* smemB = smem + 2 * ASZ;

    const int tid  = threadIdx.x;
    const int lane = tid & 63;
    const int wave = tid >> 6;
    const int wm = wave >> 1, wc = wave & 1;

    const int by = blockIdx.y;
    const bool second = (by >= ysplit);
    const GemmArgs g = second ? g1 : g0;
    const int bm = (second ? by - ysplit : by) * 128;
    const int bn = blockIdx.x * 128;

    const unsigned short* A = g.A + (long)blockIdx.z * batchA;
    const float* Bf = (const float*)g.B + (long)blockIdx.z * batchB;
    const unsigned short* Bh = (const unsigned short*)g.B + (long)blockIdx.z * batchB;

    // ---- staging geometry (wave-uniform LDS bases; per-lane global src) ----
    // A: round i covers rows i*32 + wave*8 + lane/8; 16B chunk lane%8.
    const int rA_lane = (lane >> 3);              // 0..7 within wave's 8 rows
    const int cA = (lane & 7) ^ (rA_lane & 7);    // inverse swizzle (bits 4-6)
    // B fp32: round i covers rows i*16 + wave*4 + lane/16; 16B chunk lane%16.
    const int rB_lane = (lane >> 4);              // 0..3
    const int rB7 = (wave * 4 + rB_lane) & 7;
    const int cBf = (lane & 15) ^ (rB7 << 1);     // inverse swizzle (bits 5-7)

    auto STAGE = [&](int buf, int t) {
        const long kof = (long)t * 64;
        #pragma unroll
        for (int i = 0; i < 4; i++) {
            int r = i * 32 + wave * 8 + rA_lane;
            GLL16(A + (long)(bm + r) * lda + kof + cA * 8,
                  smemA + buf * ASZ + i * 4096 + wave * 1024);
        }
        if constexpr (BF16B) {
            #pragma unroll
            for (int i = 0; i < 4; i++) {
                int r = i * 32 + wave * 8 + rA_lane;
                GLL16(Bh + (long)(bn + r) * ldb + kof + cA * 8,
                      smemB + buf * BSZ + i * 4096 + wave * 1024);
            }
        } else {
            #pragma unroll
            for (int i = 0; i < 8; i++) {
                int r = i * 16 + wave * 4 + rB_lane;
                GLL16(Bf + (long)(bn + r) * ldb + kof + cBf * 4,
                      smemB + buf * BSZ + i * 4096 + wave * 1024);
            }
        }
    };

    f32x4 acc[4][4] = {};
    const int sA = (lane & 7) << 4;     // read-side swizzle for rows r: r&7 == lane&7
    const int sB32 = (lane & 7) << 5;

    auto COMPUTE = [&](int buf) {
        #pragma unroll
        for (int ks = 0; ks < 2; ks++) {
            const int kbA = ks * 64 + (lane >> 4) * 16;   // byte offset along k (bf16)
            bf16x8 af[4], bfr[4];
            #pragma unroll
            for (int mi = 0; mi < 4; mi++) {
                int r = wm * 64 + mi * 16 + (lane & 15);
                af[mi] = *(const bf16x8*)(smemA + buf * ASZ + r * 128 + (kbA ^ sA));
            }
            if constexpr (BF16B) {
                #pragma unroll
                for (int ni = 0; ni < 4; ni++) {
                    int r = wc * 64 + ni * 16 + (lane & 15);
                    bfr[ni] = *(const bf16x8*)(smemB + buf * BSZ + r * 128 + (kbA ^ sA));
                }
            } else {
                const int kbB = ks * 128 + (lane >> 4) * 32;  // byte offset (fp32)
                #pragma unroll
                for (int ni = 0; ni < 4; ni++) {
                    int r = wc * 64 + ni * 16 + (lane & 15);
                    const char* p = smemB + buf * BSZ + r * 256 + (kbB ^ sB32);
                    float4v b0 = *(const float4v*)p;
                    float4v b1 = *(const float4v*)(p + 16);
                    bf16x8 v;
                    v[0] = (short)f2bf(b0[0]); v[1] = (short)f2bf(b0[1]);
                    v[2] = (short)f2bf(b0[2]); v[3] = (short)f2bf(b0[3]);
                    v[4] = (short)f2bf(b1[0]); v[5] = (short)f2bf(b1[1]);
                    v[6] = (short)f2bf(b1[2]); v[7] = (short)f2bf(b1[3]);
                    bfr[ni] = v;
                }
            }
            #pragma unroll
            for (int mi = 0; mi < 4; mi++)
                #pragma unroll
                for (int ni = 0; ni < 4; ni++)
                    acc[mi][ni] = __builtin_amdgcn_mfma_f32_16x16x32_bf16(
                        af[mi], bfr[ni], acc[mi][ni], 0, 0, 0);
        }
    };

    const int nk = K >> 6;
    STAGE(0, 0);
    __syncthreads();
    for (int t = 0; t < nk; ++t) {
        if (t + 1 < nk) STAGE((t + 1) & 1, t + 1);  // next tile: loads in flight
        COMPUTE(t & 1);                             // hides the load latency
        __syncthreads();                            // vmcnt drain + barrier
    }

    unsigned short* outh = (unsigned short*)g.out + (long)blockIdx.z * batchOut;
    float*          outf = (float*)g.out + (long)blockIdx.z * batchOut;
    #pragma unroll
    for (int mi = 0; mi < 4; mi++) {
        #pragma unroll
        for (int ni = 0; ni < 4; ni++) {
            int n = bn + wc * 64 + ni * 16 + (lane & 15);
            float bv = g.bias ? g.bias[n] : 0.0f;
            #pragma unroll
            for (int r = 0; r < 4; r++) {
                int m = bm + wm * 64 + mi * 16 + (lane >> 4) * 4 + r;
                float v = acc[mi][ni][r] + bv;
                long o = (long)m * ldout + n;
                if constexpr (EPI == 0) {
                    outf[o] = v;
                } else if constexpr (EPI == 1) {
                    outh[o] = f2bf(v);
                } else if constexpr (EPI == 2) {
                    float t = tanhf(0.7978845608028654f * (v + 0.044715f * v * v * v));
                    outh[o] = f2bf(0.5f * v * (1.0f + t));
                } else {
                    outf[o] = g.base[o] + g.gate[n] * v;
                }
            }
        }
    }
}

// ---------------------------------------------------------------------------
__global__ void silu_k(const float* __restrict__ x, float* __restrict__ out) {
    int i = blockIdx.x * 256 + threadIdx.x;
    if (i < DIMC) { float v = x[i]; out[i] = v / (1.0f + expf(-v)); }
}

// ---------------------------------------------------------------------------
__global__ __launch_bounds__(256)
void mod_gemv(const float* __restrict__ st,
              const float* __restrict__ Wimg, const float* __restrict__ bimg,
              const float* __restrict__ Wtxt, const float* __restrict__ btxt,
              float* __restrict__ mimg, float* __restrict__ mtxt)
{
    int wv = threadIdx.x >> 6, lane = threadIdx.x & 63;
    int r = blockIdx.x * 4 + wv;                 // 0..18431
    const float* W = blockIdx.y ? Wtxt : Wimg;
    const float* b = blockIdx.y ? btxt : bimg;
    float* out = blockIdx.y ? mtxt : mimg;
    const float* row = W + (long)r * DIMC;
    float acc = 0.f;
    #pragma unroll
    for (int j = 0; j < 12; j++) {
        float4v wvv = ((const float4v*)row)[lane + j * 64];
        float4v xv  = ((const float4v*)st)[lane + j * 64];
        acc += wvv[0] * xv[0] + wvv[1] * xv[1] + wvv[2] * xv[2] + wvv[3] * xv[3];
    }
    #pragma unroll
    for (int o = 32; o; o >>= 1) acc += __shfl_xor(acc, o);
    if (lane == 0) {
        int d = r / 6, j6 = r % 6;
        out[j6 * DIMC + d] = acc + b[r];
    }
}

// ---------------------------------------------------------------------------
__global__ __launch_bounds__(256)
void ln_mod(const float* __restrict__ x, const float* __restrict__ shift,
            const float* __restrict__ scale, unsigned short* __restrict__ out)
{
    __shared__ float red[8];
    long row = blockIdx.x;
    const float* xr = x + row * DIMC;
    float4v v[3];
    float sum = 0.f, sq = 0.f;
    #pragma unroll
    for (int j = 0; j < 3; j++) {
        v[j] = ((const float4v*)xr)[threadIdx.x + j * 256];
        #pragma unroll
        for (int c = 0; c < 4; c++) { sum += v[j][c]; sq += v[j][c] * v[j][c]; }
    }
    int lane = threadIdx.x & 63, wv = threadIdx.x >> 6;
    #pragma unroll
    for (int o = 32; o; o >>= 1) { sum += __shfl_xor(sum, o); sq += __shfl_xor(sq, o); }
    if (lane == 0) { red[wv] = sum; red[4 + wv] = sq; }
    __syncthreads();
    sum = red[0] + red[1] + red[2] + red[3];
    sq  = red[4] + red[5] + red[6] + red[7];
    float mu = sum / DIMC;
    float var = sq / DIMC - mu * mu;
    float rstd = rsqrtf(var + EPSF);
    #pragma unroll
    for (int j = 0; j < 3; j++) {
        int nb = (threadIdx.x + j * 256) * 4;
        #pragma unroll
        for (int c = 0; c < 4; c++) {
            int n = nb + c;
            float y = (v[j][c] - mu) * rstd * (scale[n] + 1.0f) + shift[n];
            out[row * DIMC + n] = f2bf(y);
        }
    }
}

// ---------------------------------------------------------------------------
__global__ __launch_bounds__(64)
void qkv_post(const float* __restrict__ qkv_img, const float* __restrict__ qkv_txt,
              const float* __restrict__ nqg, const float* __restrict__ nkg,
              const float* __restrict__ naqg, const float* __restrict__ nakg,
              const float* __restrict__ rc, const float* __restrict__ rs,
              unsigned short* __restrict__ q, unsigned short* __restrict__ k,
              unsigned short* __restrict__ vt)
{
    int s = blockIdx.x;   // 0..1279 (txt first)
    int h = blockIdx.y;
    int d0 = threadIdx.x; // 0..63
    const float *src, *gq, *gk;
    if (s < S_TXT) { src = qkv_txt + (long)s * 3 * DIMC; gq = naqg; gk = nakg; }
    else           { src = qkv_img + (long)(s - S_TXT) * 3 * DIMC; gq = nqg; gk = nkg; }

    float q0 = src[h * HD + d0],            q1 = src[h * HD + d0 + 64];
    float k0 = src[DIMC + h * HD + d0],     k1 = src[DIMC + h * HD + d0 + 64];
    float v0 = src[2 * DIMC + h * HD + d0], v1 = src[2 * DIMC + h * HD + d0 + 64];

    float sqq = q0 * q0 + q1 * q1;
    float sqk = k0 * k0 + k1 * k1;
    #pragma unroll
    for (int o = 32; o; o >>= 1) { sqq += __shfl_xor(sqq, o); sqk += __shfl_xor(sqk, o); }
    float rq = rsqrtf(sqq / (float)HD + EPSF);
    float rk = rsqrtf(sqk / (float)HD + EPSF);
    q0 *= rq * gq[d0]; q1 *= rq * gq[d0 + 64];
    k0 *= rk * gk[d0]; k1 *= rk * gk[d0 + 64];

    float qp0 = __shfl_xor(q0, 1), qp1 = __shfl_xor(q1, 1);
    float kp0 = __shfl_xor(k0, 1), kp1 = __shfl_xor(k1, 1);
    float c0 = rc[(long)s * HD + d0], c1 = rc[(long)s * HD + d0 + 64];
    float s0 = rs[(long)s * HD + d0], s1 = rs[(long)s * HD + d0 + 64];
    float sgn = (d0 & 1) ? 1.0f : -1.0f;
    float qo0 = q0 * c0 + sgn * qp0 * s0;
    float qo1 = q1 * c1 + sgn * qp1 * s1;
    float ko0 = k0 * c0 + sgn * kp0 * s0;
    float ko1 = k1 * c1 + sgn * kp1 * s1;

    const float scl = 0.08838834764831845f;   // 1/sqrt(128)
    long qkbase = ((long)h * S_TOT + s) * HD;
    q[qkbase + d0]      = f2bf(qo0 * scl);
    q[qkbase + d0 + 64] = f2bf(qo1 * scl);
    k[qkbase + d0]      = f2bf(ko0);
    k[qkbase + d0 + 64] = f2bf(ko1);
    vt[((long)h * HD + d0) * S_TOT + s]        = f2bf(v0);
    vt[((long)h * HD + d0 + 64) * S_TOT + s]   = f2bf(v1);
}

// ---------------------------------------------------------------------------
__global__ __launch_bounds__(256)
void softmax_k(unsigned short* __restrict__ scores)
{
    long row = (long)blockIdx.x * 4 + (threadIdx.x >> 6);
    int lane = threadIdx.x & 63;
    unsigned short* p = scores + row * S_TOT;
    float v[20];
    float mx = -1e30f;
    #pragma unroll
    for (int j = 0; j < 20; j++) { v[j] = b2f(p[lane + j * 64]); mx = fmaxf(mx, v[j]); }
    #pragma unroll
    for (int o = 32; o; o >>= 1) mx = fmaxf(mx, __shfl_xor(mx, o));
    float sum = 0.f;
    #pragma unroll
    for (int j = 0; j < 20; j++) { v[j] = expf(v[j] - mx); sum += v[j]; }
    #pragma unroll
    for (int o = 32; o; o >>= 1) sum += __shfl_xor(sum, o);
    float inv = 1.0f / sum;
    #pragma unroll
    for (int j = 0; j < 20; j++) p[lane + j * 64] = f2bf(v[j] * inv);
}

// ---------------------------------------------------------------------------
extern "C" void kernel_launch(void* const* d_in, const int* in_sizes, int n_in,
                              void* d_out, int out_size, void* d_ws, size_t ws_size,
                              hipStream_t stream)
{
    const float* hidden   = (const float*)d_in[0];
    const float* enc      = (const float*)d_in[1];
    const float* temb     = (const float*)d_in[2];
    const float* rope_cos = (const float*)d_in[3];
    const float* rope_sin = (const float*)d_in[4];
    const float* img_mod_w = (const float*)d_in[5];
    const float* img_mod_b = (const float*)d_in[6];
    const float* txt_mod_w = (const float*)d_in[7];
    const float* txt_mod_b = (const float*)d_in[8];
    const float* qkv_w     = (const float*)d_in[9];
    const float* qkv_b     = (const float*)d_in[10];
    const float* add_qkv_w = (const float*)d_in[11];
    const float* add_qkv_b = (const float*)d_in[12];
    const float* norm_q_g  = (const float*)d_in[13];
    const float* norm_k_g  = (const float*)d_in[14];
    const float* norm_aq_g = (const float*)d_in[15];
    const float* norm_ak_g = (const float*)d_in[16];
    const float* to_out_w  = (const float*)d_in[17];
    const float* to_out_b  = (const float*)d_in[18];
    const float* to_add_out_w = (const float*)d_in[19];
    const float* to_add_out_b = (const float*)d_in[20];
    const float* img_mlp_w1 = (const float*)d_in[21];
    const float* img_mlp_b1 = (const float*)d_in[22];
    const float* img_mlp_w2 = (const float*)d_in[23];
    const float* img_mlp_b2 = (const float*)d_in[24];
    const float* txt_mlp_w1 = (const float*)d_in[25];
    const float* txt_mlp_b1 = (const float*)d_in[26];
    const float* txt_mlp_w2 = (const float*)d_in[27];
    const float* txt_mlp_b2 = (const float*)d_in[28];

    char* w = (char*)d_ws;
    auto alloc = [&](size_t bytes) { char* p = w; w += (bytes + 255) & ~(size_t)255; return p; };
    float* silu_t  = (float*)alloc(DIMC * 4);
    float* mod_img = (float*)alloc(6 * DIMC * 4);
    float* mod_txt = (float*)alloc(6 * DIMC * 4);
    unsigned short* mA_img = (unsigned short*)alloc((long)S_IMG * DIMC * 2);
    unsigned short* mA_txt = (unsigned short*)alloc((long)S_TXT * DIMC * 2);
    float* qkv_img = (float*)alloc((long)S_IMG * 3 * DIMC * 4);
    float* qkv_txt = (float*)alloc((long)S_TXT * 3 * DIMC * 4);
    unsigned short* qb = (unsigned short*)alloc((long)HEADS * S_TOT * HD * 2);
    unsigned short* kb = (unsigned short*)alloc((long)HEADS * S_TOT * HD * 2);
    unsigned short* vt = (unsigned short*)alloc((long)HEADS * HD * S_TOT * 2);
    unsigned short* scores = (unsigned short*)alloc((long)HEADS * S_TOT * S_TOT * 2);
    unsigned short* attn = (unsigned short*)alloc((long)S_TOT * DIMC * 2);
    float* h1_img = (float*)alloc((long)S_IMG * DIMC * 4);
    float* h1_txt = (float*)alloc((long)S_TXT * DIMC * 4);
    unsigned short* gelu_img = (unsigned short*)alloc((long)S_IMG * FF * 2);
    unsigned short* gelu_txt = (unsigned short*)alloc((long)S_TXT * FF * 2);

    float* out_enc = (float*)d_out;
    float* out_hid = (float*)d_out + (long)S_TXT * DIMC;

    // 1. silu(temb), mod GEMVs
    silu_k<<<12, 256, 0, stream>>>(temb, silu_t);
    mod_gemv<<<dim3(4608, 2), 256, 0, stream>>>(silu_t, img_mod_w, img_mod_b,
                                                txt_mod_w, txt_mod_b, mod_img, mod_txt);

    // 2. LN1 + modulate -> bf16
    ln_mod<<<S_IMG, 256, 0, stream>>>(hidden, mod_img, mod_img + DIMC, mA_img);
    ln_mod<<<S_TXT, 256, 0, stream>>>(enc, mod_txt, mod_txt + DIMC, mA_txt);

    // 3. QKV GEMMs merged (img y=0..7, txt y=8..9)
    {
        GemmArgs gi{mA_img, qkv_w, qkv_b, qkv_img, nullptr, nullptr};
        GemmArgs gt{mA_txt, add_qkv_w, add_qkv_b, qkv_txt, nullptr, nullptr};
        gemm_bt<0, false><<<dim3(72, 10, 1), 256, 0, stream>>>(
            gi, gt, 8, DIMC, DIMC, DIMC, 3 * DIMC, 0, 0, 0);
    }

    // 4. RMS + RoPE + layout
    qkv_post<<<dim3(S_TOT, HEADS), 64, 0, stream>>>(
        qkv_img, qkv_txt, norm_q_g, norm_k_g, norm_aq_g, norm_ak_g,
        rope_cos, rope_sin, qb, kb, vt);

    // 5. scores = q k^T (scale folded in q), softmax, attn = P v
    {
        GemmArgs gs{qb, kb, nullptr, scores, nullptr, nullptr};
        gemm_bt<1, true><<<dim3(10, 10, HEADS), 256, 0, stream>>>(
            gs, gs, 10, HD, HD, HD, S_TOT,
            (long)S_TOT * HD, (long)S_TOT * HD, (long)S_TOT * S_TOT);
    }
    softmax_k<<<(HEADS * S_TOT) / 4, 256, 0, stream>>>(scores);
    {
        GemmArgs gp{scores, vt, nullptr, attn, nullptr, nullptr};
        gemm_bt<1, true><<<dim3(1, 10, HEADS), 256, 0, stream>>>(
            gp, gp, 10, S_TOT, S_TOT, S_TOT, DIMC,
            (long)S_TOT * S_TOT, (long)HD * S_TOT, HD);
    }

    // 6. output projections + gated residual (merged img/txt)
    {
        GemmArgs gi{attn + (long)S_TXT * DIMC, to_out_w, to_out_b, h1_img, hidden, mod_img + 2 * DIMC};
        GemmArgs gt{attn, to_add_out_w, to_add_out_b, h1_txt, enc, mod_txt + 2 * DIMC};
        gemm_bt<3, false><<<dim3(24, 10, 1), 256, 0, stream>>>(
            gi, gt, 8, DIMC, DIMC, DIMC, DIMC, 0, 0, 0);
    }

    // 7. LN2 + modulate
    ln_mod<<<S_IMG, 256, 0, stream>>>(h1_img, mod_img + 3 * DIMC, mod_img + 4 * DIMC, mA_img);
    ln_mod<<<S_TXT, 256, 0, stream>>>(h1_txt, mod_txt + 3 * DIMC, mod_txt + 4 * DIMC, mA_txt);

    // 8. MLP w1 + gelu (merged), then w2 + gated residual -> d_out (merged)
    {
        GemmArgs gi{mA_img, img_mlp_w1, img_mlp_b1, gelu_img, nullptr, nullptr};
        GemmArgs gt{mA_txt, txt_mlp_w1, txt_mlp_b1, gelu_txt, nullptr, nullptr};
        gemm_bt<2, false><<<dim3(96, 10, 1), 256, 0, stream>>>(
            gi, gt, 8, DIMC, DIMC, DIMC, FF, 0, 0, 0);
    }
    {
        GemmArgs gi{gelu_img, img_mlp_w2, img_mlp_b2, out_hid, h1_img, mod_img + 5 * DIMC};
        GemmArgs gt{gelu_txt, txt_mlp_w2, txt_mlp_b2, out_enc, h1_txt, mod_txt + 5 * DIMC};
        gemm_bt<3, false><<<dim3(24, 10, 1), 256, 0, stream>>>(
            gi, gt, 8, FF, FF, FF, DIMC, 0, 0, 0);
    }
}

// Round 4
// 863.576 us; speedup vs baseline: 1.2222x; 1.2222x over previous
//
#include <hip/hip_runtime.h>

#define DIMC   3072
#define HEADS  24
#define HD     128
#define FF     12288
#define S_IMG  1024
#define S_TXT  256
#define S_TOT  1280
#define EPSF   1e-6f

typedef __attribute__((ext_vector_type(8))) short bf16x8;
typedef __attribute__((ext_vector_type(4))) float f32x4;
typedef __attribute__((ext_vector_type(4))) float float4v;
typedef __attribute__((ext_vector_type(4))) unsigned int u32x4;

__device__ __forceinline__ unsigned short f2bf(float f) {
    union { float f; unsigned u; } c; c.f = f;
    unsigned u = c.u;
    unsigned r = (u + 0x7fffu + ((u >> 16) & 1u)) >> 16;  // RTNE
    return (unsigned short)r;
}
__device__ __forceinline__ float b2f(unsigned short h) {
    union { unsigned u; float f; } c; c.u = ((unsigned)h) << 16;
    return c.f;
}
// pack two fp32 -> two bf16 (round-half-up): 3 VALU ops
__device__ __forceinline__ unsigned packbf(float a, float b) {
    union { float f; unsigned u; } x, y; x.f = a; y.f = b;
    return __builtin_amdgcn_perm(y.u + 0x8000u, x.u + 0x8000u, 0x07060302);
}
__device__ __forceinline__ float gelu_tanh(float v) {
    float u = 1.5957691216057308f * (v + 0.044715f * v * v * v); // 2*0.79788456*
    float e = __expf(u);
    float t = 1.0f - 2.0f / (e + 1.0f);   // tanh(u/... ) note: u = 2*arg
    return 0.5f * v * (1.0f + t);
}

#define GLL16(gsrc, ldst)                                                     \
    __builtin_amdgcn_global_load_lds(                                         \
        (const __attribute__((address_space(1))) void*)(gsrc),                \
        (__attribute__((address_space(3))) void*)(ldst), 16, 0, 0)

struct GemmArgs {
    const unsigned short* A;
    const void* B;
    const float* bias;
    void* out;
    const float* base;
    const float* gate;
};

__device__ __forceinline__ void epi_store(int EPI, const GemmArgs& g,
                                          float v, long o, int) {
}

// ---------------------------------------------------------------------------
// BIG: C = A(Mx K bf16) * B(N x K fp32)^T + bias. BM=BN=256, BK=64.
// 512 threads, 8 waves (2m x 4n), wave tile 128x64, acc[8][4].
// A: global_load_lds (linear dest, pre-swizzled src). B: reg-staged fp32,
// perm-packed to bf16, ds_write into swizzled LDS. EPI: 0 fp32, 2 gelu->bf16.
// ---------------------------------------------------------------------------
template<int EPI>
__global__ __launch_bounds__(512, 2)
void gemm_big(GemmArgs g0, GemmArgs g1, int ysplit,
              int K, int lda, int ldb, int ldout)
{
    __shared__ __align__(16) char smem[131072];
    char* smemA = smem;            // 2 x 32KB
    char* smemB = smem + 65536;    // 2 x 32KB

    const int tid  = threadIdx.x;
    const int lane = tid & 63;
    const int wave = tid >> 6;
    const int wm = wave >> 2, wc = wave & 3;

    const int by = blockIdx.y;
    const bool second = (by >= ysplit);
    const GemmArgs g = second ? g1 : g0;
    const int bm = (second ? by - ysplit : by) * 256;
    const int bn = blockIdx.x * 256;

    const unsigned short* A = g.A;
    const float* Bf = (const float*)g.B;

    const int rA = lane >> 3;             // 0..7
    const int cA = (lane & 7) ^ rA;       // inverse-swizzled source chunk
    const int pB = tid & 7;               // 16B-bf16 chunk (=32B fp32)
    const int rB0 = tid >> 3;             // 0..63
    const int swB = (rB0 & 7) << 4;

    float4v breg[4][2];

    auto BLOAD = [&](int t) {
        const float* src = Bf + (long)t * 64 + pB * 8;
        #pragma unroll
        for (int i = 0; i < 4; i++) {
            const float* p = src + (long)(bn + rB0 + i * 64) * ldb;
            breg[i][0] = *(const float4v*)p;
            breg[i][1] = *(const float4v*)(p + 4);
        }
    };
    auto ASTAGE = [&](int buf, int t) {
        const long kof = (long)t * 64 + cA * 8;
        #pragma unroll
        for (int i = 0; i < 4; i++) {
            int r = i * 64 + wave * 8 + rA;
            GLL16(A + (long)(bm + r) * lda + kof,
                  smemA + buf * 32768 + i * 8192 + wave * 1024);
        }
    };
    auto BSTORE = [&](int buf) {
        #pragma unroll
        for (int i = 0; i < 4; i++) {
            int r = rB0 + i * 64;
            u32x4 w;
            w[0] = packbf(breg[i][0][0], breg[i][0][1]);
            w[1] = packbf(breg[i][0][2], breg[i][0][3]);
            w[2] = packbf(breg[i][1][0], breg[i][1][1]);
            w[3] = packbf(breg[i][1][2], breg[i][1][3]);
            *(u32x4*)(smemB + buf * 32768 + r * 128 + ((pB * 16) ^ swB)) = w;
        }
    };

    f32x4 acc[8][4] = {};
    auto COMPUTE = [&](int buf) {
        #pragma unroll
        for (int ks = 0; ks < 2; ks++) {
            const int kb = ks * 64 + (lane >> 4) * 16;
            bf16x8 af[8], bfr[4];
            #pragma unroll
            for (int mi = 0; mi < 8; mi++) {
                int r = wm * 128 + mi * 16 + (lane & 15);
                af[mi] = *(const bf16x8*)(smemA + buf * 32768 + r * 128 + (kb ^ ((r & 7) << 4)));
            }
            #pragma unroll
            for (int ni = 0; ni < 4; ni++) {
                int r = wc * 64 + ni * 16 + (lane & 15);
                bfr[ni] = *(const bf16x8*)(smemB + buf * 32768 + r * 128 + (kb ^ ((r & 7) << 4)));
            }
            #pragma unroll
            for (int mi = 0; mi < 8; mi++)
                #pragma unroll
                for (int ni = 0; ni < 4; ni++)
                    acc[mi][ni] = __builtin_amdgcn_mfma_f32_16x16x32_bf16(
                        af[mi], bfr[ni], acc[mi][ni], 0, 0, 0);
        }
    };

    const int nk = K >> 6;
    BLOAD(0);
    ASTAGE(0, 0);
    BSTORE(0);
    __syncthreads();
    for (int t = 0; t < nk; ++t) {
        const int cur = t & 1;
        if (t + 1 < nk) {
            BLOAD(t + 1);
            ASTAGE(cur ^ 1, t + 1);
        }
        __builtin_amdgcn_sched_barrier(0);
        COMPUTE(cur);
        __builtin_amdgcn_sched_barrier(0);
        if (t + 1 < nk) BSTORE(cur ^ 1);
        __syncthreads();
    }

    unsigned short* outh = (unsigned short*)g.out;
    float*          outf = (float*)g.out;
    #pragma unroll
    for (int mi = 0; mi < 8; mi++) {
        #pragma unroll
        for (int ni = 0; ni < 4; ni++) {
            int n = bn + wc * 64 + ni * 16 + (lane & 15);
            float bv = g.bias ? g.bias[n] : 0.0f;
            #pragma unroll
            for (int r = 0; r < 4; r++) {
                int m = bm + wm * 128 + mi * 16 + (lane >> 4) * 4 + r;
                float v = acc[mi][ni][r] + bv;
                long o = (long)m * ldout + n;
                if constexpr (EPI == 0) outf[o] = v;
                else                    outh[o] = f2bf(gelu_tanh(v));
            }
        }
    }
}

// ---------------------------------------------------------------------------
// 128x128 tile, BK=64, 4 waves. BF16B=true: both operands bf16 via
// global_load_lds. BF16B=false: A via GLL, B fp32 reg-staged -> bf16 LDS.
// EPI: 0 fp32; 1 bf16; 2 gelu->bf16; 3 base + gate*v -> fp32
// ---------------------------------------------------------------------------
template<int EPI, bool BF16B>
__global__ __launch_bounds__(256)
void gemm_bt(GemmArgs g0, GemmArgs g1, int ysplit,
             int K, int lda, int ldb, int ldout,
             long batchA, long batchB, long batchOut)
{
    __shared__ __align__(16) char smem[65536];
    char* smemA = smem;            // 2 x 16KB
    char* smemB = smem + 32768;    // 2 x 16KB

    const int tid  = threadIdx.x;
    const int lane = tid & 63;
    const int wave = tid >> 6;
    const int wm = wave >> 1, wc = wave & 1;

    const int by = blockIdx.y;
    const bool second = (by >= ysplit);
    const GemmArgs g = second ? g1 : g0;
    const int bm = (second ? by - ysplit : by) * 128;
    const int bn = blockIdx.x * 128;

    const unsigned short* A = g.A + (long)blockIdx.z * batchA;
    const float* Bf = (const float*)g.B + (long)blockIdx.z * batchB;
    const unsigned short* Bh = (const unsigned short*)g.B + (long)blockIdx.z * batchB;

    const int rA = lane >> 3;             // 0..7
    const int cA = (lane & 7) ^ rA;       // inverse-swizzled source chunk
    const int pB = tid & 7;
    const int rB0 = tid >> 3;             // 0..31
    const int swB = (rB0 & 7) << 4;

    float4v breg[4][2];

    auto BLOAD = [&](int t) {
        const float* src = Bf + (long)t * 64 + pB * 8;
        #pragma unroll
        for (int i = 0; i < 4; i++) {
            const float* p = src + (long)(bn + rB0 + i * 32) * ldb;
            breg[i][0] = *(const float4v*)p;
            breg[i][1] = *(const float4v*)(p + 4);
        }
    };
    auto STAGE_A = [&](int buf, int t) {
        const long kof = (long)t * 64 + cA * 8;
        #pragma unroll
        for (int i = 0; i < 4; i++) {
            int r = i * 32 + wave * 8 + rA;
            GLL16(A + (long)(bm + r) * lda + kof,
                  smemA + buf * 16384 + i * 4096 + wave * 1024);
        }
    };
    auto STAGE_B16 = [&](int buf, int t) {
        const long kof = (long)t * 64 + cA * 8;
        #pragma unroll
        for (int i = 0; i < 4; i++) {
            int r = i * 32 + wave * 8 + rA;
            GLL16(Bh + (long)(bn + r) * ldb + kof,
                  smemB + buf * 16384 + i * 4096 + wave * 1024);
        }
    };
    auto BSTORE = [&](int buf) {
        #pragma unroll
        for (int i = 0; i < 4; i++) {
            int r = rB0 + i * 32;
            u32x4 w;
            w[0] = packbf(breg[i][0][0], breg[i][0][1]);
            w[1] = packbf(breg[i][0][2], breg[i][0][3]);
            w[2] = packbf(breg[i][1][0], breg[i][1][1]);
            w[3] = packbf(breg[i][1][2], breg[i][1][3]);
            *(u32x4*)(smemB + buf * 16384 + r * 128 + ((pB * 16) ^ swB)) = w;
        }
    };

    f32x4 acc[4][4] = {};
    auto COMPUTE = [&](int buf) {
        #pragma unroll
        for (int ks = 0; ks < 2; ks++) {
            const int kb = ks * 64 + (lane >> 4) * 16;
            bf16x8 af[4], bfr[4];
            #pragma unroll
            for (int mi = 0; mi < 4; mi++) {
                int r = wm * 64 + mi * 16 + (lane & 15);
                af[mi] = *(const bf16x8*)(smemA + buf * 16384 + r * 128 + (kb ^ ((r & 7) << 4)));
            }
            #pragma unroll
            for (int ni = 0; ni < 4; ni++) {
                int r = wc * 64 + ni * 16 + (lane & 15);
                bfr[ni] = *(const bf16x8*)(smemB + buf * 16384 + r * 128 + (kb ^ ((r & 7) << 4)));
            }
            #pragma unroll
            for (int mi = 0; mi < 4; mi++)
                #pragma unroll
                for (int ni = 0; ni < 4; ni++)
                    acc[mi][ni] = __builtin_amdgcn_mfma_f32_16x16x32_bf16(
                        af[mi], bfr[ni], acc[mi][ni], 0, 0, 0);
        }
    };

    const int nk = K >> 6;
    if constexpr (BF16B) {
        STAGE_A(0, 0); STAGE_B16(0, 0);
    } else {
        BLOAD(0); STAGE_A(0, 0); BSTORE(0);
    }
    __syncthreads();
    for (int t = 0; t < nk; ++t) {
        const int cur = t & 1;
        if (t + 1 < nk) {
            if constexpr (BF16B) {
                STAGE_A(cur ^ 1, t + 1); STAGE_B16(cur ^ 1, t + 1);
            } else {
                BLOAD(t + 1); STAGE_A(cur ^ 1, t + 1);
            }
        }
        __builtin_amdgcn_sched_barrier(0);
        COMPUTE(cur);
        __builtin_amdgcn_sched_barrier(0);
        if constexpr (!BF16B) { if (t + 1 < nk) BSTORE(cur ^ 1); }
        __syncthreads();
    }

    unsigned short* outh = (unsigned short*)g.out + (long)blockIdx.z * batchOut;
    float*          outf = (float*)g.out + (long)blockIdx.z * batchOut;
    #pragma unroll
    for (int mi = 0; mi < 4; mi++) {
        #pragma unroll
        for (int ni = 0; ni < 4; ni++) {
            int n = bn + wc * 64 + ni * 16 + (lane & 15);
            float bv = g.bias ? g.bias[n] : 0.0f;
            #pragma unroll
            for (int r = 0; r < 4; r++) {
                int m = bm + wm * 64 + mi * 16 + (lane >> 4) * 4 + r;
                float v = acc[mi][ni][r] + bv;
                long o = (long)m * ldout + n;
                if constexpr (EPI == 0)      outf[o] = v;
                else if constexpr (EPI == 1) outh[o] = f2bf(v);
                else if constexpr (EPI == 2) outh[o] = f2bf(gelu_tanh(v));
                else                         outf[o] = g.base[o] + g.gate[n] * v;
            }
        }
    }
}

// ---------------------------------------------------------------------------
__global__ void silu_k(const float* __restrict__ x, float* __restrict__ out) {
    int i = blockIdx.x * 256 + threadIdx.x;
    if (i < DIMC) { float v = x[i]; out[i] = v / (1.0f + expf(-v)); }
}

// ---------------------------------------------------------------------------
__global__ __launch_bounds__(256)
void mod_gemv(const float* __restrict__ st,
              const float* __restrict__ Wimg, const float* __restrict__ bimg,
              const float* __restrict__ Wtxt, const float* __restrict__ btxt,
              float* __restrict__ mimg, float* __restrict__ mtxt)
{
    int wv = threadIdx.x >> 6, lane = threadIdx.x & 63;
    int r = blockIdx.x * 4 + wv;                 // 0..18431
    const float* W = blockIdx.y ? Wtxt : Wimg;
    const float* b = blockIdx.y ? btxt : bimg;
    float* out = blockIdx.y ? mtxt : mimg;
    const float* row = W + (long)r * DIMC;
    float acc = 0.f;
    #pragma unroll
    for (int j = 0; j < 12; j++) {
        float4v wvv = ((const float4v*)row)[lane + j * 64];
        float4v xv  = ((const float4v*)st)[lane + j * 64];
        acc += wvv[0] * xv[0] + wvv[1] * xv[1] + wvv[2] * xv[2] + wvv[3] * xv[3];
    }
    #pragma unroll
    for (int o = 32; o; o >>= 1) acc += __shfl_xor(acc, o);
    if (lane == 0) {
        int d = r / 6, j6 = r % 6;
        out[j6 * DIMC + d] = acc + b[r];
    }
}

// ---------------------------------------------------------------------------
__global__ __launch_bounds__(256)
void ln_mod(const float* __restrict__ x, const float* __restrict__ shift,
            const float* __restrict__ scale, unsigned short* __restrict__ out)
{
    __shared__ float red[8];
    long row = blockIdx.x;
    const float* xr = x + row * DIMC;
    float4v v[3];
    float sum = 0.f, sq = 0.f;
    #pragma unroll
    for (int j = 0; j < 3; j++) {
        v[j] = ((const float4v*)xr)[threadIdx.x + j * 256];
        #pragma unroll
        for (int c = 0; c < 4; c++) { sum += v[j][c]; sq += v[j][c] * v[j][c]; }
    }
    int lane = threadIdx.x & 63, wv = threadIdx.x >> 6;
    #pragma unroll
    for (int o = 32; o; o >>= 1) { sum += __shfl_xor(sum, o); sq += __shfl_xor(sq, o); }
    if (lane == 0) { red[wv] = sum; red[4 + wv] = sq; }
    __syncthreads();
    sum = red[0] + red[1] + red[2] + red[3];
    sq  = red[4] + red[5] + red[6] + red[7];
    float mu = sum / DIMC;
    float var = sq / DIMC - mu * mu;
    float rstd = rsqrtf(var + EPSF);
    #pragma unroll
    for (int j = 0; j < 3; j++) {
        int nb = (threadIdx.x + j * 256) * 4;
        #pragma unroll
        for (int c = 0; c < 4; c++) {
            int n = nb + c;
            float y = (v[j][c] - mu) * rstd * (scale[n] + 1.0f) + shift[n];
            out[row * DIMC + n] = f2bf(y);
        }
    }
}

// ---------------------------------------------------------------------------
__global__ __launch_bounds__(64)
void qkv_post(const float* __restrict__ qkv_img, const float* __restrict__ qkv_txt,
              const float* __restrict__ nqg, const float* __restrict__ nkg,
              const float* __restrict__ naqg, const float* __restrict__ nakg,
              const float* __restrict__ rc, const float* __restrict__ rs,
              unsigned short* __restrict__ q, unsigned short* __restrict__ k,
              unsigned short* __restrict__ vt)
{
    int s = blockIdx.x;   // 0..1279 (txt first)
    int h = blockIdx.y;
    int d0 = threadIdx.x; // 0..63
    const float *src, *gq, *gk;
    if (s < S_TXT) { src = qkv_txt + (long)s * 3 * DIMC; gq = naqg; gk = nakg; }
    else           { src = qkv_img + (long)(s - S_TXT) * 3 * DIMC; gq = nqg; gk = nkg; }

    float q0 = src[h * HD + d0],            q1 = src[h * HD + d0 + 64];
    float k0 = src[DIMC + h * HD + d0],     k1 = src[DIMC + h * HD + d0 + 64];
    float v0 = src[2 * DIMC + h * HD + d0], v1 = src[2 * DIMC + h * HD + d0 + 64];

    float sqq = q0 * q0 + q1 * q1;
    float sqk = k0 * k0 + k1 * k1;
    #pragma unroll
    for (int o = 32; o; o >>= 1) { sqq += __shfl_xor(sqq, o); sqk += __shfl_xor(sqk, o); }
    float rq = rsqrtf(sqq / (float)HD + EPSF);
    float rk = rsqrtf(sqk / (float)HD + EPSF);
    q0 *= rq * gq[d0]; q1 *= rq * gq[d0 + 64];
    k0 *= rk * gk[d0]; k1 *= rk * gk[d0 + 64];

    float qp0 = __shfl_xor(q0, 1), qp1 = __shfl_xor(q1, 1);
    float kp0 = __shfl_xor(k0, 1), kp1 = __shfl_xor(k1, 1);
    float c0 = rc[(long)s * HD + d0], c1 = rc[(long)s * HD + d0 + 64];
    float s0 = rs[(long)s * HD + d0], s1 = rs[(long)s * HD + d0 + 64];
    float sgn = (d0 & 1) ? 1.0f : -1.0f;
    float qo0 = q0 * c0 + sgn * qp0 * s0;
    float qo1 = q1 * c1 + sgn * qp1 * s1;
    float ko0 = k0 * c0 + sgn * kp0 * s0;
    float ko1 = k1 * c1 + sgn * kp1 * s1;

    const float scl = 0.08838834764831845f;   // 1/sqrt(128)
    long qkbase = ((long)h * S_TOT + s) * HD;
    q[qkbase + d0]      = f2bf(qo0 * scl);
    q[qkbase + d0 + 64] = f2bf(qo1 * scl);
    k[qkbase + d0]      = f2bf(ko0);
    k[qkbase + d0 + 64] = f2bf(ko1);
    vt[((long)h * HD + d0) * S_TOT + s]        = f2bf(v0);
    vt[((long)h * HD + d0 + 64) * S_TOT + s]   = f2bf(v1);
}

// ---------------------------------------------------------------------------
__global__ __launch_bounds__(256)
void softmax_k(unsigned short* __restrict__ scores)
{
    long row = (long)blockIdx.x * 4 + (threadIdx.x >> 6);
    int lane = threadIdx.x & 63;
    unsigned short* p = scores + row * S_TOT;
    float v[20];
    float mx = -1e30f;
    #pragma unroll
    for (int j = 0; j < 20; j++) { v[j] = b2f(p[lane + j * 64]); mx = fmaxf(mx, v[j]); }
    #pragma unroll
    for (int o = 32; o; o >>= 1) mx = fmaxf(mx, __shfl_xor(mx, o));
    float sum = 0.f;
    #pragma unroll
    for (int j = 0; j < 20; j++) { v[j] = __expf(v[j] - mx); sum += v[j]; }
    #pragma unroll
    for (int o = 32; o; o >>= 1) sum += __shfl_xor(sum, o);
    float inv = 1.0f / sum;
    #pragma unroll
    for (int j = 0; j < 20; j++) p[lane + j * 64] = f2bf(v[j] * inv);
}

// ---------------------------------------------------------------------------
extern "C" void kernel_launch(void* const* d_in, const int* in_sizes, int n_in,
                              void* d_out, int out_size, void* d_ws, size_t ws_size,
                              hipStream_t stream)
{
    const float* hidden   = (const float*)d_in[0];
    const float* enc      = (const float*)d_in[1];
    const float* temb     = (const float*)d_in[2];
    const float* rope_cos = (const float*)d_in[3];
    const float* rope_sin = (const float*)d_in[4];
    const float* img_mod_w = (const float*)d_in[5];
    const float* img_mod_b = (const float*)d_in[6];
    const float* txt_mod_w = (const float*)d_in[7];
    const float* txt_mod_b = (const float*)d_in[8];
    const float* qkv_w     = (const float*)d_in[9];
    const float* qkv_b     = (const float*)d_in[10];
    const float* add_qkv_w = (const float*)d_in[11];
    const float* add_qkv_b = (const float*)d_in[12];
    const float* norm_q_g  = (const float*)d_in[13];
    const float* norm_k_g  = (const float*)d_in[14];
    const float* norm_aq_g = (const float*)d_in[15];
    const float* norm_ak_g = (const float*)d_in[16];
    const float* to_out_w  = (const float*)d_in[17];
    const float* to_out_b  = (const float*)d_in[18];
    const float* to_add_out_w = (const float*)d_in[19];
    const float* to_add_out_b = (const float*)d_in[20];
    const float* img_mlp_w1 = (const float*)d_in[21];
    const float* img_mlp_b1 = (const float*)d_in[22];
    const float* img_mlp_w2 = (const float*)d_in[23];
    const float* img_mlp_b2 = (const float*)d_in[24];
    const float* txt_mlp_w1 = (const float*)d_in[25];
    const float* txt_mlp_b1 = (const float*)d_in[26];
    const float* txt_mlp_w2 = (const float*)d_in[27];
    const float* txt_mlp_b2 = (const float*)d_in[28];

    char* w = (char*)d_ws;
    auto alloc = [&](size_t bytes) { char* p = w; w += (bytes + 255) & ~(size_t)255; return p; };
    float* silu_t  = (float*)alloc(DIMC * 4);
    float* mod_img = (float*)alloc(6 * DIMC * 4);
    float* mod_txt = (float*)alloc(6 * DIMC * 4);
    unsigned short* mA_img = (unsigned short*)alloc((long)S_IMG * DIMC * 2);
    unsigned short* mA_txt = (unsigned short*)alloc((long)S_TXT * DIMC * 2);
    float* qkv_img = (float*)alloc((long)S_IMG * 3 * DIMC * 4);
    float* qkv_txt = (float*)alloc((long)S_TXT * 3 * DIMC * 4);
    unsigned short* qb = (unsigned short*)alloc((long)HEADS * S_TOT * HD * 2);
    unsigned short* kb = (unsigned short*)alloc((long)HEADS * S_TOT * HD * 2);
    unsigned short* vt = (unsigned short*)alloc((long)HEADS * HD * S_TOT * 2);
    unsigned short* scores = (unsigned short*)alloc((long)HEADS * S_TOT * S_TOT * 2);
    unsigned short* attn = (unsigned short*)alloc((long)S_TOT * DIMC * 2);
    float* h1_img = (float*)alloc((long)S_IMG * DIMC * 4);
    float* h1_txt = (float*)alloc((long)S_TXT * DIMC * 4);
    unsigned short* gelu_img = (unsigned short*)alloc((long)S_IMG * FF * 2);
    unsigned short* gelu_txt = (unsigned short*)alloc((long)S_TXT * FF * 2);

    float* out_enc = (float*)d_out;
    float* out_hid = (float*)d_out + (long)S_TXT * DIMC;

    // 1. silu(temb), mod GEMVs
    silu_k<<<12, 256, 0, stream>>>(temb, silu_t);
    mod_gemv<<<dim3(4608, 2), 256, 0, stream>>>(silu_t, img_mod_w, img_mod_b,
                                                txt_mod_w, txt_mod_b, mod_img, mod_txt);

    // 2. LN1 + modulate -> bf16
    ln_mod<<<S_IMG, 256, 0, stream>>>(hidden, mod_img, mod_img + DIMC, mA_img);
    ln_mod<<<S_TXT, 256, 0, stream>>>(enc, mod_txt, mod_txt + DIMC, mA_txt);

    // 3. QKV GEMMs merged (img y=0..3, txt y=4) on 256x256 tiles
    {
        GemmArgs gi{mA_img, qkv_w, qkv_b, qkv_img, nullptr, nullptr};
        GemmArgs gt{mA_txt, add_qkv_w, add_qkv_b, qkv_txt, nullptr, nullptr};
        gemm_big<0><<<dim3(36, 5), 512, 0, stream>>>(
            gi, gt, 4, DIMC, DIMC, DIMC, 3 * DIMC);
    }

    // 4. RMS + RoPE + layout
    qkv_post<<<dim3(S_TOT, HEADS), 64, 0, stream>>>(
        qkv_img, qkv_txt, norm_q_g, norm_k_g, norm_aq_g, norm_ak_g,
        rope_cos, rope_sin, qb, kb, vt);

    // 5. scores = q k^T (scale folded in q), softmax, attn = P v
    {
        GemmArgs gs{qb, kb, nullptr, scores, nullptr, nullptr};
        gemm_bt<1, true><<<dim3(10, 10, HEADS), 256, 0, stream>>>(
            gs, gs, 10, HD, HD, HD, S_TOT,
            (long)S_TOT * HD, (long)S_TOT * HD, (long)S_TOT * S_TOT);
    }
    softmax_k<<<(HEADS * S_TOT) / 4, 256, 0, stream>>>(scores);
    {
        GemmArgs gp{scores, vt, nullptr, attn, nullptr, nullptr};
        gemm_bt<1, true><<<dim3(1, 10, HEADS), 256, 0, stream>>>(
            gp, gp, 10, S_TOT, S_TOT, S_TOT, DIMC,
            (long)S_TOT * S_TOT, (long)HD * S_TOT, HD);
    }

    // 6. output projections + gated residual (merged img/txt), 128x128 tiles
    {
        GemmArgs gi{attn + (long)S_TXT * DIMC, to_out_w, to_out_b, h1_img, hidden, mod_img + 2 * DIMC};
        GemmArgs gt{attn, to_add_out_w, to_add_out_b, h1_txt, enc, mod_txt + 2 * DIMC};
        gemm_bt<3, false><<<dim3(24, 10), 256, 0, stream>>>(
            gi, gt, 8, DIMC, DIMC, DIMC, DIMC, 0, 0, 0);
    }

    // 7. LN2 + modulate
    ln_mod<<<S_IMG, 256, 0, stream>>>(h1_img, mod_img + 3 * DIMC, mod_img + 4 * DIMC, mA_img);
    ln_mod<<<S_TXT, 256, 0, stream>>>(h1_txt, mod_txt + 3 * DIMC, mod_txt + 4 * DIMC, mA_txt);

    // 8. MLP w1 + gelu on 256x256 tiles; w2 + gated residual on 128x128
    {
        GemmArgs gi{mA_img, img_mlp_w1, img_mlp_b1, gelu_img, nullptr, nullptr};
        GemmArgs gt{mA_txt, txt_mlp_w1, txt_mlp_b1, gelu_txt, nullptr, nullptr};
        gemm_big<2><<<dim3(48, 5), 512, 0, stream>>>(
            gi, gt, 4, DIMC, DIMC, DIMC, FF);
    }
    {
        GemmArgs gi{gelu_img, img_mlp_w2, img_mlp_b2, out_hid, h1_img, mod_img + 5 * DIMC};
        GemmArgs gt{gelu_txt, txt_mlp_w2, txt_mlp_b2, out_enc, h1_txt, mod_txt + 5 * DIMC};
        gemm_bt<3, false><<<dim3(24, 10), 256, 0, stream>>>(
            gi, gt, 8, FF, FF, FF, DIMC, 0, 0, 0);
    }
}

// Round 5
// 764.987 us; speedup vs baseline: 1.3798x; 1.1289x over previous
//
#include <hip/hip_runtime.h>

#define DIMC   3072
#define HEADS  24
#define HD     128
#define FF     12288
#define S_IMG  1024
#define S_TXT  256
#define S_TOT  1280
#define EPSF   1e-6f

typedef __attribute__((ext_vector_type(8))) short bf16x8;
typedef __attribute__((ext_vector_type(4))) float f32x4;
typedef __attribute__((ext_vector_type(4))) float float4v;
typedef __attribute__((ext_vector_type(4))) unsigned int u32x4;

__device__ __forceinline__ unsigned short f2bf(float f) {
    union { float f; unsigned u; } c; c.f = f;
    unsigned u = c.u;
    unsigned r = (u + 0x7fffu + ((u >> 16) & 1u)) >> 16;  // RTNE
    return (unsigned short)r;
}
__device__ __forceinline__ float b2f(unsigned short h) {
    union { unsigned u; float f; } c; c.u = ((unsigned)h) << 16;
    return c.f;
}
// pack two fp32 -> two bf16 (round-half-up): 3 VALU ops
__device__ __forceinline__ unsigned packbf(float a, float b) {
    union { float f; unsigned u; } x, y; x.f = a; y.f = b;
    return __builtin_amdgcn_perm(y.u + 0x8000u, x.u + 0x8000u, 0x07060302);
}
__device__ __forceinline__ float gelu_tanh(float v) {
    float u = 1.5957691216057308f * (v + 0.044715f * v * v * v);
    float e = __expf(u);
    float t = 1.0f - 2.0f / (e + 1.0f);
    return 0.5f * v * (1.0f + t);
}

#define GLL16(gsrc, ldst)                                                     \
    __builtin_amdgcn_global_load_lds(                                         \
        (const __attribute__((address_space(1))) void*)(gsrc),                \
        (__attribute__((address_space(3))) void*)(ldst), 16, 0, 0)

struct GemmArgs {
    const unsigned short* A;
    const void* B;
    const float* bias;
    void* out;
    long bOut;          // out advance per blockIdx.z
};

// ---------------------------------------------------------------------------
// BIG: C = A(MxK bf16) * B(NxK fp32)^T + bias. BM=BN=256, BK=64.
// 512 threads, 8 waves (2m x 4n). A: global_load_lds; B: reg-staged fp32 ->
// perm-packed bf16 -> swizzled LDS. EPI: 0 fp32+bias, 2 gelu->bf16.
// ---------------------------------------------------------------------------
template<int EPI>
__global__ __launch_bounds__(512, 2)
void gemm_big(GemmArgs g0, GemmArgs g1, int ysplit,
              int K, int lda, int ldb, int ldout)
{
    __shared__ __align__(16) char smem[131072];
    char* smemA = smem;            // 2 x 32KB
    char* smemB = smem + 65536;    // 2 x 32KB

    const int tid  = threadIdx.x;
    const int lane = tid & 63;
    const int wave = tid >> 6;
    const int wm = wave >> 2, wc = wave & 3;

    const int by = blockIdx.y;
    const bool second = (by >= ysplit);
    const GemmArgs g = second ? g1 : g0;
    const int bm = (second ? by - ysplit : by) * 256;
    const int bn = blockIdx.x * 256;

    const unsigned short* A = g.A;
    const float* Bf = (const float*)g.B;

    const int rA = lane >> 3;
    const int cA = (lane & 7) ^ rA;
    const int pB = tid & 7;
    const int rB0 = tid >> 3;             // 0..63
    const int swB = (rB0 & 7) << 4;

    float4v breg[4][2];

    auto BLOAD = [&](int t) {
        const float* src = Bf + (long)t * 64 + pB * 8;
        #pragma unroll
        for (int i = 0; i < 4; i++) {
            const float* p = src + (long)(bn + rB0 + i * 64) * ldb;
            breg[i][0] = *(const float4v*)p;
            breg[i][1] = *(const float4v*)(p + 4);
        }
    };
    auto ASTAGE = [&](int buf, int t) {
        const long kof = (long)t * 64 + cA * 8;
        #pragma unroll
        for (int i = 0; i < 4; i++) {
            int r = i * 64 + wave * 8 + rA;
            GLL16(A + (long)(bm + r) * lda + kof,
                  smemA + buf * 32768 + i * 8192 + wave * 1024);
        }
    };
    auto BSTORE = [&](int buf) {
        #pragma unroll
        for (int i = 0; i < 4; i++) {
            int r = rB0 + i * 64;
            u32x4 w;
            w[0] = packbf(breg[i][0][0], breg[i][0][1]);
            w[1] = packbf(breg[i][0][2], breg[i][0][3]);
            w[2] = packbf(breg[i][1][0], breg[i][1][1]);
            w[3] = packbf(breg[i][1][2], breg[i][1][3]);
            *(u32x4*)(smemB + buf * 32768 + r * 128 + ((pB * 16) ^ swB)) = w;
        }
    };

    f32x4 acc[8][4] = {};
    auto COMPUTE = [&](int buf) {
        #pragma unroll
        for (int ks = 0; ks < 2; ks++) {
            const int kb = ks * 64 + (lane >> 4) * 16;
            bf16x8 af[8], bfr[4];
            #pragma unroll
            for (int mi = 0; mi < 8; mi++) {
                int r = wm * 128 + mi * 16 + (lane & 15);
                af[mi] = *(const bf16x8*)(smemA + buf * 32768 + r * 128 + (kb ^ ((r & 7) << 4)));
            }
            #pragma unroll
            for (int ni = 0; ni < 4; ni++) {
                int r = wc * 64 + ni * 16 + (lane & 15);
                bfr[ni] = *(const bf16x8*)(smemB + buf * 32768 + r * 128 + (kb ^ ((r & 7) << 4)));
            }
            #pragma unroll
            for (int mi = 0; mi < 8; mi++)
                #pragma unroll
                for (int ni = 0; ni < 4; ni++)
                    acc[mi][ni] = __builtin_amdgcn_mfma_f32_16x16x32_bf16(
                        af[mi], bfr[ni], acc[mi][ni], 0, 0, 0);
        }
    };

    const int nk = K >> 6;
    BLOAD(0);
    ASTAGE(0, 0);
    BSTORE(0);
    __syncthreads();
    for (int t = 0; t < nk; ++t) {
        const int cur = t & 1;
        if (t + 1 < nk) {
            BLOAD(t + 1);
            ASTAGE(cur ^ 1, t + 1);
        }
        __builtin_amdgcn_sched_barrier(0);
        COMPUTE(cur);
        __builtin_amdgcn_sched_barrier(0);
        if (t + 1 < nk) BSTORE(cur ^ 1);
        __syncthreads();
    }

    unsigned short* outh = (unsigned short*)g.out;
    float*          outf = (float*)g.out;
    #pragma unroll
    for (int mi = 0; mi < 8; mi++) {
        #pragma unroll
        for (int ni = 0; ni < 4; ni++) {
            int n = bn + wc * 64 + ni * 16 + (lane & 15);
            float bv = g.bias ? g.bias[n] : 0.0f;
            #pragma unroll
            for (int r = 0; r < 4; r++) {
                int m = bm + wm * 128 + mi * 16 + (lane >> 4) * 4 + r;
                float v = acc[mi][ni][r] + bv;
                long o = (long)m * ldout + n;
                if constexpr (EPI == 0) outf[o] = v;
                else                    outh[o] = f2bf(gelu_tanh(v));
            }
        }
    }
}

// ---------------------------------------------------------------------------
// 128x128 tile, BK=64, 4 waves. BF16B=true: both operands via global_load_lds.
// BF16B=false: A via GLL, B fp32 reg-staged -> bf16 LDS.
// Split-K: blockIdx.z advances A/B by batchA/batchB elements, out by g.bOut.
// EPI: 0 fp32(+bias); 1 bf16(+bias)
// ---------------------------------------------------------------------------
template<int EPI, bool BF16B>
__global__ __launch_bounds__(256)
void gemm_bt(GemmArgs g0, GemmArgs g1, int ysplit,
             int K, int lda, int ldb, int ldout,
             long batchA, long batchB)
{
    __shared__ __align__(16) char smem[65536];
    char* smemA = smem;            // 2 x 16KB
    char* smemB = smem + 32768;    // 2 x 16KB

    const int tid  = threadIdx.x;
    const int lane = tid & 63;
    const int wave = tid >> 6;
    const int wm = wave >> 1, wc = wave & 1;

    const int by = blockIdx.y;
    const bool second = (by >= ysplit);
    const GemmArgs g = second ? g1 : g0;
    const int bm = (second ? by - ysplit : by) * 128;
    const int bn = blockIdx.x * 128;

    const unsigned short* A = g.A + (long)blockIdx.z * batchA;
    const float* Bf = (const float*)g.B + (long)blockIdx.z * batchB;
    const unsigned short* Bh = (const unsigned short*)g.B + (long)blockIdx.z * batchB;

    const int rA = lane >> 3;
    const int cA = (lane & 7) ^ rA;
    const int pB = tid & 7;
    const int rB0 = tid >> 3;             // 0..31
    const int swB = (rB0 & 7) << 4;

    float4v breg[4][2];

    auto BLOAD = [&](int t) {
        const float* src = Bf + (long)t * 64 + pB * 8;
        #pragma unroll
        for (int i = 0; i < 4; i++) {
            const float* p = src + (long)(bn + rB0 + i * 32) * ldb;
            breg[i][0] = *(const float4v*)p;
            breg[i][1] = *(const float4v*)(p + 4);
        }
    };
    auto STAGE_A = [&](int buf, int t) {
        const long kof = (long)t * 64 + cA * 8;
        #pragma unroll
        for (int i = 0; i < 4; i++) {
            int r = i * 32 + wave * 8 + rA;
            GLL16(A + (long)(bm + r) * lda + kof,
                  smemA + buf * 16384 + i * 4096 + wave * 1024);
        }
    };
    auto STAGE_B16 = [&](int buf, int t) {
        const long kof = (long)t * 64 + cA * 8;
        #pragma unroll
        for (int i = 0; i < 4; i++) {
            int r = i * 32 + wave * 8 + rA;
            GLL16(Bh + (long)(bn + r) * ldb + kof,
                  smemB + buf * 16384 + i * 4096 + wave * 1024);
        }
    };
    auto BSTORE = [&](int buf) {
        #pragma unroll
        for (int i = 0; i < 4; i++) {
            int r = rB0 + i * 32;
            u32x4 w;
            w[0] = packbf(breg[i][0][0], breg[i][0][1]);
            w[1] = packbf(breg[i][0][2], breg[i][0][3]);
            w[2] = packbf(breg[i][1][0], breg[i][1][1]);
            w[3] = packbf(breg[i][1][2], breg[i][1][3]);
            *(u32x4*)(smemB + buf * 16384 + r * 128 + ((pB * 16) ^ swB)) = w;
        }
    };

    f32x4 acc[4][4] = {};
    auto COMPUTE = [&](int buf) {
        #pragma unroll
        for (int ks = 0; ks < 2; ks++) {
            const int kb = ks * 64 + (lane >> 4) * 16;
            bf16x8 af[4], bfr[4];
            #pragma unroll
            for (int mi = 0; mi < 4; mi++) {
                int r = wm * 64 + mi * 16 + (lane & 15);
                af[mi] = *(const bf16x8*)(smemA + buf * 16384 + r * 128 + (kb ^ ((r & 7) << 4)));
            }
            #pragma unroll
            for (int ni = 0; ni < 4; ni++) {
                int r = wc * 64 + ni * 16 + (lane & 15);
                bfr[ni] = *(const bf16x8*)(smemB + buf * 16384 + r * 128 + (kb ^ ((r & 7) << 4)));
            }
            #pragma unroll
            for (int mi = 0; mi < 4; mi++)
                #pragma unroll
                for (int ni = 0; ni < 4; ni++)
                    acc[mi][ni] = __builtin_amdgcn_mfma_f32_16x16x32_bf16(
                        af[mi], bfr[ni], acc[mi][ni], 0, 0, 0);
        }
    };

    const int nk = K >> 6;
    if constexpr (BF16B) {
        STAGE_A(0, 0); STAGE_B16(0, 0);
    } else {
        BLOAD(0); STAGE_A(0, 0); BSTORE(0);
    }
    __syncthreads();
    for (int t = 0; t < nk; ++t) {
        const int cur = t & 1;
        if (t + 1 < nk) {
            if constexpr (BF16B) {
                STAGE_A(cur ^ 1, t + 1); STAGE_B16(cur ^ 1, t + 1);
            } else {
                BLOAD(t + 1); STAGE_A(cur ^ 1, t + 1);
            }
        }
        __builtin_amdgcn_sched_barrier(0);
        COMPUTE(cur);
        __builtin_amdgcn_sched_barrier(0);
        if constexpr (!BF16B) { if (t + 1 < nk) BSTORE(cur ^ 1); }
        __syncthreads();
    }

    unsigned short* outh = (unsigned short*)g.out + (long)blockIdx.z * g.bOut;
    float*          outf = (float*)g.out + (long)blockIdx.z * g.bOut;
    #pragma unroll
    for (int mi = 0; mi < 4; mi++) {
        #pragma unroll
        for (int ni = 0; ni < 4; ni++) {
            int n = bn + wc * 64 + ni * 16 + (lane & 15);
            float bv = g.bias ? g.bias[n] : 0.0f;
            #pragma unroll
            for (int r = 0; r < 4; r++) {
                int m = bm + wm * 64 + mi * 16 + (lane >> 4) * 4 + r;
                float v = acc[mi][ni][r] + bv;
                long o = (long)m * ldout + n;
                if constexpr (EPI == 0)      outf[o] = v;
                else                         outh[o] = f2bf(v);
            }
        }
    }
}

// ---------------------------------------------------------------------------
__global__ void silu_k(const float* __restrict__ x, float* __restrict__ out) {
    int i = blockIdx.x * 256 + threadIdx.x;
    if (i < DIMC) { float v = x[i]; out[i] = v / (1.0f + expf(-v)); }
}

// ---------------------------------------------------------------------------
__global__ __launch_bounds__(256)
void mod_gemv(const float* __restrict__ st,
              const float* __restrict__ Wimg, const float* __restrict__ bimg,
              const float* __restrict__ Wtxt, const float* __restrict__ btxt,
              float* __restrict__ mimg, float* __restrict__ mtxt)
{
    int wv = threadIdx.x >> 6, lane = threadIdx.x & 63;
    int r = blockIdx.x * 4 + wv;                 // 0..18431
    const float* W = blockIdx.y ? Wtxt : Wimg;
    const float* b = blockIdx.y ? btxt : bimg;
    float* out = blockIdx.y ? mtxt : mimg;
    const float* row = W + (long)r * DIMC;
    float acc = 0.f;
    #pragma unroll
    for (int j = 0; j < 12; j++) {
        float4v wvv = ((const float4v*)row)[lane + j * 64];
        float4v xv  = ((const float4v*)st)[lane + j * 64];
        acc += wvv[0] * xv[0] + wvv[1] * xv[1] + wvv[2] * xv[2] + wvv[3] * xv[3];
    }
    #pragma unroll
    for (int o = 32; o; o >>= 1) acc += __shfl_xor(acc, o);
    if (lane == 0) {
        int d = r / 6, j6 = r % 6;
        out[j6 * DIMC + d] = acc + b[r];
    }
}

// ---------------------------------------------------------------------------
__global__ __launch_bounds__(256)
void ln_mod(const float* __restrict__ x, const float* __restrict__ shift,
            const float* __restrict__ scale, unsigned short* __restrict__ out)
{
    __shared__ float red[8];
    long row = blockIdx.x;
    const float* xr = x + row * DIMC;
    float4v v[3];
    float sum = 0.f, sq = 0.f;
    #pragma unroll
    for (int j = 0; j < 3; j++) {
        v[j] = ((const float4v*)xr)[threadIdx.x + j * 256];
        #pragma unroll
        for (int c = 0; c < 4; c++) { sum += v[j][c]; sq += v[j][c] * v[j][c]; }
    }
    int lane = threadIdx.x & 63, wv = threadIdx.x >> 6;
    #pragma unroll
    for (int o = 32; o; o >>= 1) { sum += __shfl_xor(sum, o); sq += __shfl_xor(sq, o); }
    if (lane == 0) { red[wv] = sum; red[4 + wv] = sq; }
    __syncthreads();
    sum = red[0] + red[1] + red[2] + red[3];
    sq  = red[4] + red[5] + red[6] + red[7];
    float mu = sum / DIMC;
    float var = sq / DIMC - mu * mu;
    float rstd = rsqrtf(var + EPSF);
    #pragma unroll
    for (int j = 0; j < 3; j++) {
        int nb = (threadIdx.x + j * 256) * 4;
        #pragma unroll
        for (int c = 0; c < 4; c++) {
            int n = nb + c;
            float y = (v[j][c] - mu) * rstd * (scale[n] + 1.0f) + shift[n];
            out[row * DIMC + n] = f2bf(y);
        }
    }
}

// ---------------------------------------------------------------------------
// proj reduce + gated residual + LN2 + modulate, fused.
// h1 = base + gate1*(pbias + p0 + p1); mA = ln(h1)*(scale2+1)+shift2
// ---------------------------------------------------------------------------
__global__ __launch_bounds__(256)
void reduce_ln(const float* __restrict__ p0, const float* __restrict__ p1,
               const float* __restrict__ pbias, const float* __restrict__ base,
               const float* __restrict__ gate1, const float* __restrict__ shift2,
               const float* __restrict__ scale2,
               float* __restrict__ h1, unsigned short* __restrict__ mA)
{
    __shared__ float red[8];
    long off = (long)blockIdx.x * DIMC;
    float4v v[3];
    float sum = 0.f, sq = 0.f;
    #pragma unroll
    for (int j = 0; j < 3; j++) {
        int idx = threadIdx.x + j * 256;
        float4v a  = ((const float4v*)(base + off))[idx];
        float4v q0 = ((const float4v*)(p0 + off))[idx];
        float4v q1 = ((const float4v*)(p1 + off))[idx];
        float4v gb = ((const float4v*)pbias)[idx];
        float4v gt = ((const float4v*)gate1)[idx];
        #pragma unroll
        for (int c = 0; c < 4; c++) {
            float val = a[c] + gt[c] * (gb[c] + q0[c] + q1[c]);
            v[j][c] = val; sum += val; sq += val * val;
        }
        ((float4v*)(h1 + off))[idx] = v[j];
    }
    int lane = threadIdx.x & 63, wv = threadIdx.x >> 6;
    #pragma unroll
    for (int o = 32; o; o >>= 1) { sum += __shfl_xor(sum, o); sq += __shfl_xor(sq, o); }
    if (lane == 0) { red[wv] = sum; red[4 + wv] = sq; }
    __syncthreads();
    sum = red[0] + red[1] + red[2] + red[3];
    sq  = red[4] + red[5] + red[6] + red[7];
    float mu = sum / DIMC;
    float rstd = rsqrtf(sq / DIMC - mu * mu + EPSF);
    #pragma unroll
    for (int j = 0; j < 3; j++) {
        int nb = (threadIdx.x + j * 256) * 4;
        #pragma unroll
        for (int c = 0; c < 4; c++) {
            int n = nb + c;
            float y = (v[j][c] - mu) * rstd * (scale2[n] + 1.0f) + shift2[n];
            mA[off + n] = f2bf(y);
        }
    }
}

// ---------------------------------------------------------------------------
// w2 reduce: out = h1 + gate2*(wbias + p0+p1+p2+p3). PS = split stride.
// ---------------------------------------------------------------------------
__global__ __launch_bounds__(256)
void reduce_out(const float* __restrict__ p, long PS,
                const float* __restrict__ h1, const float* __restrict__ wbias,
                const float* __restrict__ gate2, float* __restrict__ out, int n4)
{
    int i = blockIdx.x * 256 + threadIdx.x;
    if (i >= n4) return;
    int n = (i * 4) % DIMC;
    float4v s = ((const float4v*)p)[i];
    float4v s1 = ((const float4v*)(p + PS))[i];
    float4v s2 = ((const float4v*)(p + 2 * PS))[i];
    float4v s3 = ((const float4v*)(p + 3 * PS))[i];
    float4v h = ((const float4v*)h1)[i];
    float4v bv = *(const float4v*)(wbias + n);
    float4v gv = *(const float4v*)(gate2 + n);
    float4v r;
    #pragma unroll
    for (int c = 0; c < 4; c++)
        r[c] = h[c] + gv[c] * (bv[c] + s[c] + s1[c] + s2[c] + s3[c]);
    ((float4v*)out)[i] = r;
}

// ---------------------------------------------------------------------------
__global__ __launch_bounds__(64)
void qkv_post(const float* __restrict__ qkv_img, const float* __restrict__ qkv_txt,
              const float* __restrict__ nqg, const float* __restrict__ nkg,
              const float* __restrict__ naqg, const float* __restrict__ nakg,
              const float* __restrict__ rc, const float* __restrict__ rs,
              unsigned short* __restrict__ q, unsigned short* __restrict__ k,
              unsigned short* __restrict__ vt)
{
    int s = blockIdx.x;   // 0..1279 (txt first)
    int h = blockIdx.y;
    int d0 = threadIdx.x; // 0..63
    const float *src, *gq, *gk;
    if (s < S_TXT) { src = qkv_txt + (long)s * 3 * DIMC; gq = naqg; gk = nakg; }
    else           { src = qkv_img + (long)(s - S_TXT) * 3 * DIMC; gq = nqg; gk = nkg; }

    float q0 = src[h * HD + d0],            q1 = src[h * HD + d0 + 64];
    float k0 = src[DIMC + h * HD + d0],     k1 = src[DIMC + h * HD + d0 + 64];
    float v0 = src[2 * DIMC + h * HD + d0], v1 = src[2 * DIMC + h * HD + d0 + 64];

    float sqq = q0 * q0 + q1 * q1;
    float sqk = k0 * k0 + k1 * k1;
    #pragma unroll
    for (int o = 32; o; o >>= 1) { sqq += __shfl_xor(sqq, o); sqk += __shfl_xor(sqk, o); }
    float rq = rsqrtf(sqq / (float)HD + EPSF);
    float rk = rsqrtf(sqk / (float)HD + EPSF);
    q0 *= rq * gq[d0]; q1 *= rq * gq[d0 + 64];
    k0 *= rk * gk[d0]; k1 *= rk * gk[d0 + 64];

    float qp0 = __shfl_xor(q0, 1), qp1 = __shfl_xor(q1, 1);
    float kp0 = __shfl_xor(k0, 1), kp1 = __shfl_xor(k1, 1);
    float c0 = rc[(long)s * HD + d0], c1 = rc[(long)s * HD + d0 + 64];
    float s0 = rs[(long)s * HD + d0], s1 = rs[(long)s * HD + d0 + 64];
    float sgn = (d0 & 1) ? 1.0f : -1.0f;
    float qo0 = q0 * c0 + sgn * qp0 * s0;
    float qo1 = q1 * c1 + sgn * qp1 * s1;
    float ko0 = k0 * c0 + sgn * kp0 * s0;
    float ko1 = k1 * c1 + sgn * kp1 * s1;

    const float scl = 0.08838834764831845f;   // 1/sqrt(128)
    long qkbase = ((long)h * S_TOT + s) * HD;
    q[qkbase + d0]      = f2bf(qo0 * scl);
    q[qkbase + d0 + 64] = f2bf(qo1 * scl);
    k[qkbase + d0]      = f2bf(ko0);
    k[qkbase + d0 + 64] = f2bf(ko1);
    vt[((long)h * HD + d0) * S_TOT + s]        = f2bf(v0);
    vt[((long)h * HD + d0 + 64) * S_TOT + s]   = f2bf(v1);
}

// ---------------------------------------------------------------------------
__global__ __launch_bounds__(256)
void softmax_k(unsigned short* __restrict__ scores)
{
    long row = (long)blockIdx.x * 4 + (threadIdx.x >> 6);
    int lane = threadIdx.x & 63;
    unsigned short* p = scores + row * S_TOT;
    float v[20];
    float mx = -1e30f;
    #pragma unroll
    for (int j = 0; j < 20; j++) { v[j] = b2f(p[lane + j * 64]); mx = fmaxf(mx, v[j]); }
    #pragma unroll
    for (int o = 32; o; o >>= 1) mx = fmaxf(mx, __shfl_xor(mx, o));
    float sum = 0.f;
    #pragma unroll
    for (int j = 0; j < 20; j++) { v[j] = __expf(v[j] - mx); sum += v[j]; }
    #pragma unroll
    for (int o = 32; o; o >>= 1) sum += __shfl_xor(sum, o);
    float inv = 1.0f / sum;
    #pragma unroll
    for (int j = 0; j < 20; j++) p[lane + j * 64] = f2bf(v[j] * inv);
}

// ---------------------------------------------------------------------------
extern "C" void kernel_launch(void* const* d_in, const int* in_sizes, int n_in,
                              void* d_out, int out_size, void* d_ws, size_t ws_size,
                              hipStream_t stream)
{
    const float* hidden   = (const float*)d_in[0];
    const float* enc      = (const float*)d_in[1];
    const float* temb     = (const float*)d_in[2];
    const float* rope_cos = (const float*)d_in[3];
    const float* rope_sin = (const float*)d_in[4];
    const float* img_mod_w = (const float*)d_in[5];
    const float* img_mod_b = (const float*)d_in[6];
    const float* txt_mod_w = (const float*)d_in[7];
    const float* txt_mod_b = (const float*)d_in[8];
    const float* qkv_w     = (const float*)d_in[9];
    const float* qkv_b     = (const float*)d_in[10];
    const float* add_qkv_w = (const float*)d_in[11];
    const float* add_qkv_b = (const float*)d_in[12];
    const float* norm_q_g  = (const float*)d_in[13];
    const float* norm_k_g  = (const float*)d_in[14];
    const float* norm_aq_g = (const float*)d_in[15];
    const float* norm_ak_g = (const float*)d_in[16];
    const float* to_out_w  = (const float*)d_in[17];
    const float* to_out_b  = (const float*)d_in[18];
    const float* to_add_out_w = (const float*)d_in[19];
    const float* to_add_out_b = (const float*)d_in[20];
    const float* img_mlp_w1 = (const float*)d_in[21];
    const float* img_mlp_b1 = (const float*)d_in[22];
    const float* img_mlp_w2 = (const float*)d_in[23];
    const float* img_mlp_b2 = (const float*)d_in[24];
    const float* txt_mlp_w1 = (const float*)d_in[25];
    const float* txt_mlp_b1 = (const float*)d_in[26];
    const float* txt_mlp_w2 = (const float*)d_in[27];
    const float* txt_mlp_b2 = (const float*)d_in[28];

    char* w = (char*)d_ws;
    auto alloc = [&](size_t bytes) { char* p = w; w += (bytes + 255) & ~(size_t)255; return p; };
    float* silu_t  = (float*)alloc(DIMC * 4);
    float* mod_img = (float*)alloc(6 * DIMC * 4);
    float* mod_txt = (float*)alloc(6 * DIMC * 4);
    unsigned short* mA_img = (unsigned short*)alloc((long)S_IMG * DIMC * 2);
    unsigned short* mA_txt = (unsigned short*)alloc((long)S_TXT * DIMC * 2);
    float* qkv_img = (float*)alloc((long)S_IMG * 3 * DIMC * 4);
    float* qkv_txt = (float*)alloc((long)S_TXT * 3 * DIMC * 4);
    unsigned short* qb = (unsigned short*)alloc((long)HEADS * S_TOT * HD * 2);
    unsigned short* kb = (unsigned short*)alloc((long)HEADS * S_TOT * HD * 2);
    unsigned short* vt = (unsigned short*)alloc((long)HEADS * HD * S_TOT * 2);
    unsigned short* scores = (unsigned short*)alloc((long)HEADS * S_TOT * S_TOT * 2);
    unsigned short* attn = (unsigned short*)alloc((long)S_TOT * DIMC * 2);
    float* h1_img = (float*)alloc((long)S_IMG * DIMC * 4);
    float* h1_txt = (float*)alloc((long)S_TXT * DIMC * 4);
    unsigned short* gelu_img = (unsigned short*)alloc((long)S_IMG * FF * 2);
    unsigned short* gelu_txt = (unsigned short*)alloc((long)S_TXT * FF * 2);

    // split-K partials alias the scores region (dead outside attention)
    const long PS = (long)S_TOT * DIMC;             // 1280*3072 per split
    float* part = (float*)scores;                    // up to 4*PS = 63MB <= 78.6MB
    float* part_img = part;                          // img rows at offset 0
    float* part_txt = part + (long)S_IMG * DIMC;     // txt rows after img

    float* out_enc = (float*)d_out;
    float* out_hid = (float*)d_out + (long)S_TXT * DIMC;

    // 1. silu(temb), mod GEMVs
    silu_k<<<12, 256, 0, stream>>>(temb, silu_t);
    mod_gemv<<<dim3(4608, 2), 256, 0, stream>>>(silu_t, img_mod_w, img_mod_b,
                                                txt_mod_w, txt_mod_b, mod_img, mod_txt);

    // 2. LN1 + modulate -> bf16
    ln_mod<<<S_IMG, 256, 0, stream>>>(hidden, mod_img, mod_img + DIMC, mA_img);
    ln_mod<<<S_TXT, 256, 0, stream>>>(enc, mod_txt, mod_txt + DIMC, mA_txt);

    // 3. QKV GEMMs merged (img y=0..3, txt y=4) on 256x256 tiles
    {
        GemmArgs gi{mA_img, qkv_w, qkv_b, qkv_img, 0};
        GemmArgs gt{mA_txt, add_qkv_w, add_qkv_b, qkv_txt, 0};
        gemm_big<0><<<dim3(36, 5), 512, 0, stream>>>(
            gi, gt, 4, DIMC, DIMC, DIMC, 3 * DIMC);
    }

    // 4. RMS + RoPE + layout
    qkv_post<<<dim3(S_TOT, HEADS), 64, 0, stream>>>(
        qkv_img, qkv_txt, norm_q_g, norm_k_g, norm_aq_g, norm_ak_g,
        rope_cos, rope_sin, qb, kb, vt);

    // 5. scores = q k^T (scale folded in q), softmax, attn = P v
    {
        GemmArgs gs{qb, kb, nullptr, scores, (long)S_TOT * S_TOT};
        gemm_bt<1, true><<<dim3(10, 10, HEADS), 256, 0, stream>>>(
            gs, gs, 10, HD, HD, HD, S_TOT,
            (long)S_TOT * HD, (long)S_TOT * HD);
    }
    softmax_k<<<(HEADS * S_TOT) / 4, 256, 0, stream>>>(scores);
    {
        GemmArgs gp{scores, vt, nullptr, attn, HD};
        gemm_bt<1, true><<<dim3(1, 10, HEADS), 256, 0, stream>>>(
            gp, gp, 10, S_TOT, S_TOT, S_TOT, DIMC,
            (long)S_TOT * S_TOT, (long)HD * S_TOT);
    }

    // 6. output projections: split-K x2 -> raw partials (alias scores)
    {
        GemmArgs gi{attn + (long)S_TXT * DIMC, to_out_w, nullptr, part_img, PS};
        GemmArgs gt{attn, to_add_out_w, nullptr, part_txt, PS};
        gemm_bt<0, false><<<dim3(24, 10, 2), 256, 0, stream>>>(
            gi, gt, 8, 1536, DIMC, DIMC, DIMC, 1536, 1536);
    }

    // 7. reduce + gated residual + LN2 + modulate (fused)
    reduce_ln<<<S_IMG, 256, 0, stream>>>(
        part_img, part_img + PS, to_out_b, hidden,
        mod_img + 2 * DIMC, mod_img + 3 * DIMC, mod_img + 4 * DIMC,
        h1_img, mA_img);
    reduce_ln<<<S_TXT, 256, 0, stream>>>(
        part_txt, part_txt + PS, to_add_out_b, enc,
        mod_txt + 2 * DIMC, mod_txt + 3 * DIMC, mod_txt + 4 * DIMC,
        h1_txt, mA_txt);

    // 8. MLP w1 + gelu on 256x256 tiles
    {
        GemmArgs gi{mA_img, img_mlp_w1, img_mlp_b1, gelu_img, 0};
        GemmArgs gt{mA_txt, txt_mlp_w1, txt_mlp_b1, gelu_txt, 0};
        gemm_big<2><<<dim3(48, 5), 512, 0, stream>>>(
            gi, gt, 4, DIMC, DIMC, DIMC, FF);
    }

    // 9. w2: split-K x4 -> raw partials, then reduce + gated residual -> d_out
    {
        GemmArgs gi{gelu_img, img_mlp_w2, nullptr, part_img, PS};
        GemmArgs gt{gelu_txt, txt_mlp_w2, nullptr, part_txt, PS};
        gemm_bt<0, false><<<dim3(24, 10, 4), 256, 0, stream>>>(
            gi, gt, 8, 3072, FF, FF, DIMC, 3072, 3072);
    }
    reduce_out<<<(S_IMG * DIMC / 4 + 255) / 256, 256, 0, stream>>>(
        part_img, PS, h1_img, img_mlp_b2, mod_img + 5 * DIMC, out_hid,
        S_IMG * DIMC / 4);
    reduce_out<<<(S_TXT * DIMC / 4 + 255) / 256, 256, 0, stream>>>(
        part_txt, PS, h1_txt, txt_mlp_b2, mod_txt + 5 * DIMC, out_enc,
        S_TXT * DIMC / 4);
}